// Round 7
// baseline (1035.819 us; speedup 1.0000x reference)
//
#include <hip/hip_runtime.h>

typedef __bf16 bf16x8 __attribute__((ext_vector_type(8)));
typedef float f32x4 __attribute__((ext_vector_type(4)));

union U8 { uint4 u; bf16x8 b; };

__device__ inline float bf16f(unsigned short h) {
    return __uint_as_float(((unsigned)h) << 16);
}

__device__ inline unsigned short f32_to_bf16_rn(float f) {
    unsigned u = __float_as_uint(f);
    unsigned rounding = 0x7FFFu + ((u >> 16) & 1u);
    u += rounding;
    return (unsigned short)(u >> 16);
}

__device__ inline double wsum(double v) {
    #pragma unroll
    for (int m = 32; m; m >>= 1) v += __shfl_xor(v, m, 64);
    return v;
}
__device__ inline double wmin(double v) {
    #pragma unroll
    for (int m = 32; m; m >>= 1) v = fmin(v, __shfl_xor(v, m, 64));
    return v;
}
__device__ inline double wmax(double v) {
    #pragma unroll
    for (int m = 32; m; m >>= 1) v = fmax(v, __shfl_xor(v, m, 64));
    return v;
}

// ---------------------------------------------------------------------------
// Kernel 0: pre-split fp32 -> 3 bf16 planes (h+m+l) for X and W.
// ---------------------------------------------------------------------------
__global__ __launch_bounds__(256) void split_kernel(
    const float* __restrict__ X, const float* __restrict__ W,
    unsigned short* __restrict__ Xh, unsigned short* __restrict__ Xm, unsigned short* __restrict__ Xl,
    unsigned short* __restrict__ Wh, unsigned short* __restrict__ Wm, unsigned short* __restrict__ Wl)
{
    size_t i4 = (size_t)blockIdx.x * 256 + threadIdx.x;   // float4 index, total 3145728
    const float* src; unsigned short *ph, *pm, *pl; size_t off4;
    if (i4 < 1048576) { src = X; ph = Xh; pm = Xm; pl = Xl; off4 = i4; }
    else              { src = W; ph = Wh; pm = Wm; pl = Wl; off4 = i4 - 1048576; }

    float4 v = ((const float4*)src)[off4];
    ushort4 h, m, l;
    float r1;
    h.x = f32_to_bf16_rn(v.x); r1 = v.x - bf16f(h.x);
    m.x = f32_to_bf16_rn(r1);  l.x = f32_to_bf16_rn(r1 - bf16f(m.x));
    h.y = f32_to_bf16_rn(v.y); r1 = v.y - bf16f(h.y);
    m.y = f32_to_bf16_rn(r1);  l.y = f32_to_bf16_rn(r1 - bf16f(m.y));
    h.z = f32_to_bf16_rn(v.z); r1 = v.z - bf16f(h.z);
    m.z = f32_to_bf16_rn(r1);  l.z = f32_to_bf16_rn(r1 - bf16f(m.z));
    h.w = f32_to_bf16_rn(v.w); r1 = v.w - bf16f(h.w);
    m.w = f32_to_bf16_rn(r1);  l.w = f32_to_bf16_rn(r1 - bf16f(m.w));

    ((ushort4*)ph)[off4] = h;
    ((ushort4*)pm)[off4] = m;
    ((ushort4*)pl)[off4] = l;
}

// ---------------------------------------------------------------------------
// Kernel 1 (v3): 6-plane bf16 GEMM, VGPR-staged software pipeline.
// Tile t+1 is prefetched into VGPRs (global_load_dwordx4 -> private dest, so
// __syncthreads needs NO vmcnt drain), MFMAs run on the LDS-resident tile t,
// then the prefetch is ds_written after the barrier. Single 48 KB LDS buffer
// keeps occupancy; XCD-aware swizzle (8 rects of 4x16 tiles) for L2 locality.
// ---------------------------------------------------------------------------
__global__ __launch_bounds__(256) void gemm_pipe(
    const unsigned short* __restrict__ Xh, const unsigned short* __restrict__ Xm,
    const unsigned short* __restrict__ Xl,
    const unsigned short* __restrict__ Wh, const unsigned short* __restrict__ Wm,
    const unsigned short* __restrict__ Wl,
    const float* __restrict__ biasf, float* __restrict__ M)
{
    const int K = 2048, N = 4096;
    __shared__ unsigned short S[6][128][32];   // 48 KB single buffer

    int tid  = threadIdx.x;
    // XCD swizzle: hardware round-robins linear id % 8 across XCDs; make each
    // XCD own a 4(by) x 16(bx) rectangle of tiles.
    int id = blockIdx.x + gridDim.x * blockIdx.y;   // 0..511
    int c  = id & 7;
    int s  = id >> 3;                               // 0..63
    int by = (c >> 1) * 4 + (s & 3);                // 0..15
    int bx = (c & 1) * 16 + (s >> 2);               // 0..31
    int m0 = by * 128;
    int n0 = bx * 128;

    int wave = tid >> 6;
    int lane = tid & 63;
    int wm   = (wave >> 1) * 64;
    int wn   = (wave & 1) * 64;
    int l16  = lane & 15;
    int quad = lane >> 4;

    const unsigned short* gp[6];
    gp[0] = Xh + (size_t)m0 * K;
    gp[1] = Xm + (size_t)m0 * K;
    gp[2] = Xl + (size_t)m0 * K;
    gp[3] = Wh + (size_t)n0 * K;
    gp[4] = Wm + (size_t)n0 * K;
    gp[5] = Wl + (size_t)n0 * K;

    int rloc = lane >> 2;            // 0..15
    int cloc = (lane & 3) << 3;      // 0,8,16,24 ushorts
    unsigned off0 = (unsigned)((16 * wave + rloc) * K + cloc);  // q=0, ushort units
    unsigned off1 = off0 + 64u * K;                              // q=1

    f32x4 acc[4][4];
    #pragma unroll
    for (int mi = 0; mi < 4; ++mi)
        #pragma unroll
        for (int ni = 0; ni < 4; ++ni)
            acc[mi][ni] = f32x4{0.f, 0.f, 0.f, 0.f};

    // LDS write target for this lane (byte addr): plane p, wave, q
    char* sbase = (char*)&S[0][0][0] + wave * 1024 + lane * 16;

    // ---- prologue: stage tile 0 ----
    {
        uint4 st[12];
        #pragma unroll
        for (int p = 0; p < 6; ++p) {
            st[p * 2 + 0] = *(const uint4*)(gp[p] + off0);
            st[p * 2 + 1] = *(const uint4*)(gp[p] + off1);
        }
        #pragma unroll
        for (int p = 0; p < 6; ++p) {
            *(uint4*)(sbase + p * 8192)        = st[p * 2 + 0];
            *(uint4*)(sbase + p * 8192 + 4096) = st[p * 2 + 1];
        }
    }
    __syncthreads();

    for (int t = 0; t < 64; ++t) {
        // prefetch tile t+1 into VGPRs (private: no barrier drain needed)
        uint4 st[12];
        if (t < 63) {
            unsigned k0 = (unsigned)(t + 1) * 32u;
            #pragma unroll
            for (int p = 0; p < 6; ++p) {
                st[p * 2 + 0] = *(const uint4*)(gp[p] + off0 + k0);
                st[p * 2 + 1] = *(const uint4*)(gp[p] + off1 + k0);
            }
        }

        // fragments from LDS tile t + MFMA
        U8 ah[4], am[4], al[4], bh[4], bm[4], bl[4];
        #pragma unroll
        for (int mi = 0; mi < 4; ++mi) {
            ah[mi].u = *(const uint4*)&S[0][wm + mi * 16 + l16][quad * 8];
            am[mi].u = *(const uint4*)&S[1][wm + mi * 16 + l16][quad * 8];
            al[mi].u = *(const uint4*)&S[2][wm + mi * 16 + l16][quad * 8];
        }
        #pragma unroll
        for (int ni = 0; ni < 4; ++ni) {
            bh[ni].u = *(const uint4*)&S[3][wn + ni * 16 + l16][quad * 8];
            bm[ni].u = *(const uint4*)&S[4][wn + ni * 16 + l16][quad * 8];
            bl[ni].u = *(const uint4*)&S[5][wn + ni * 16 + l16][quad * 8];
        }

        #pragma unroll
        for (int mi = 0; mi < 4; ++mi)
            #pragma unroll
            for (int ni = 0; ni < 4; ++ni) {
                acc[mi][ni] = __builtin_amdgcn_mfma_f32_16x16x32_bf16(
                    al[mi].b, bh[ni].b, acc[mi][ni], 0, 0, 0);
                acc[mi][ni] = __builtin_amdgcn_mfma_f32_16x16x32_bf16(
                    ah[mi].b, bl[ni].b, acc[mi][ni], 0, 0, 0);
                acc[mi][ni] = __builtin_amdgcn_mfma_f32_16x16x32_bf16(
                    am[mi].b, bm[ni].b, acc[mi][ni], 0, 0, 0);
                acc[mi][ni] = __builtin_amdgcn_mfma_f32_16x16x32_bf16(
                    am[mi].b, bh[ni].b, acc[mi][ni], 0, 0, 0);
                acc[mi][ni] = __builtin_amdgcn_mfma_f32_16x16x32_bf16(
                    ah[mi].b, bm[ni].b, acc[mi][ni], 0, 0, 0);
                acc[mi][ni] = __builtin_amdgcn_mfma_f32_16x16x32_bf16(
                    ah[mi].b, bh[ni].b, acc[mi][ni], 0, 0, 0);
            }

        __syncthreads();   // all waves done reading tile t (lgkm only, no vmcnt)
        if (t < 63) {
            #pragma unroll
            for (int p = 0; p < 6; ++p) {
                *(uint4*)(sbase + p * 8192)        = st[p * 2 + 0];
                *(uint4*)(sbase + p * 8192 + 4096) = st[p * 2 + 1];
            }
            __syncthreads();   // tile t+1 visible
        }
    }

    // epilogue: C/D layout col = lane&15, row = quad*4 + reg
    #pragma unroll
    for (int ni = 0; ni < 4; ++ni) {
        int col = n0 + wn + ni * 16 + l16;
        float bv = biasf[col];
        #pragma unroll
        for (int mi = 0; mi < 4; ++mi) {
            int row = m0 + wm + mi * 16 + quad * 4;
            #pragma unroll
            for (int r = 0; r < 4; ++r)
                M[(size_t)(row + r) * N + col] = acc[mi][ni][r] + bv;
        }
    }
}

// ---------------------------------------------------------------------------
// Kernel 1-fallback: round-3 in-kernel split GEMM (used only if ws too small).
// ---------------------------------------------------------------------------
__global__ __launch_bounds__(256) void gemm_bt(const float* __restrict__ Xf,
                                               const float* __restrict__ Wf,
                                               const float* __restrict__ biasf,
                                               float* __restrict__ M)
{
    const int K = 2048, N = 4096;
    __shared__ unsigned short AsH[128][32];
    __shared__ unsigned short AsM[128][32];
    __shared__ unsigned short AsL[128][32];
    __shared__ unsigned short BsH[128][32];
    __shared__ unsigned short BsM[128][32];
    __shared__ unsigned short BsL[128][32];

    int tid  = threadIdx.x;
    int m0   = blockIdx.y * 128;
    int n0   = blockIdx.x * 128;
    int wid  = tid >> 6;
    int lane = tid & 63;
    int wm   = (wid >> 1) * 64;
    int wn   = (wid & 1) * 64;
    int l16  = lane & 15;
    int quad = lane >> 4;

    f32x4 acc[4][4];
    #pragma unroll
    for (int mi = 0; mi < 4; ++mi)
        #pragma unroll
        for (int ni = 0; ni < 4; ++ni)
            acc[mi][ni] = f32x4{0.f, 0.f, 0.f, 0.f};

    for (int k0 = 0; k0 < K; k0 += 32) {
        #pragma unroll
        for (int s = 0; s < 4; ++s) {
            int c  = tid + s * 256;
            int r  = c >> 3;
            int kc = (c & 7) << 2;
            {
                float4 v = *(const float4*)&Xf[(size_t)(m0 + r) * K + k0 + kc];
                ushort4 h, mm_, l; float r1;
                h.x = f32_to_bf16_rn(v.x); r1 = v.x - bf16f(h.x);
                mm_.x = f32_to_bf16_rn(r1); l.x = f32_to_bf16_rn(r1 - bf16f(mm_.x));
                h.y = f32_to_bf16_rn(v.y); r1 = v.y - bf16f(h.y);
                mm_.y = f32_to_bf16_rn(r1); l.y = f32_to_bf16_rn(r1 - bf16f(mm_.y));
                h.z = f32_to_bf16_rn(v.z); r1 = v.z - bf16f(h.z);
                mm_.z = f32_to_bf16_rn(r1); l.z = f32_to_bf16_rn(r1 - bf16f(mm_.z));
                h.w = f32_to_bf16_rn(v.w); r1 = v.w - bf16f(h.w);
                mm_.w = f32_to_bf16_rn(r1); l.w = f32_to_bf16_rn(r1 - bf16f(mm_.w));
                *(ushort4*)&AsH[r][kc] = h; *(ushort4*)&AsM[r][kc] = mm_; *(ushort4*)&AsL[r][kc] = l;
            }
            {
                float4 v = *(const float4*)&Wf[(size_t)(n0 + r) * K + k0 + kc];
                ushort4 h, mm_, l; float r1;
                h.x = f32_to_bf16_rn(v.x); r1 = v.x - bf16f(h.x);
                mm_.x = f32_to_bf16_rn(r1); l.x = f32_to_bf16_rn(r1 - bf16f(mm_.x));
                h.y = f32_to_bf16_rn(v.y); r1 = v.y - bf16f(h.y);
                mm_.y = f32_to_bf16_rn(r1); l.y = f32_to_bf16_rn(r1 - bf16f(mm_.y));
                h.z = f32_to_bf16_rn(v.z); r1 = v.z - bf16f(h.z);
                mm_.z = f32_to_bf16_rn(r1); l.z = f32_to_bf16_rn(r1 - bf16f(mm_.z));
                h.w = f32_to_bf16_rn(v.w); r1 = v.w - bf16f(h.w);
                mm_.w = f32_to_bf16_rn(r1); l.w = f32_to_bf16_rn(r1 - bf16f(mm_.w));
                *(ushort4*)&BsH[r][kc] = h; *(ushort4*)&BsM[r][kc] = mm_; *(ushort4*)&BsL[r][kc] = l;
            }
        }
        __syncthreads();

        U8 ah[4], am[4], al[4], bh[4], bm[4], bl[4];
        #pragma unroll
        for (int mi = 0; mi < 4; ++mi) {
            ah[mi].u = *(const uint4*)&AsH[wm + mi * 16 + l16][quad * 8];
            am[mi].u = *(const uint4*)&AsM[wm + mi * 16 + l16][quad * 8];
            al[mi].u = *(const uint4*)&AsL[wm + mi * 16 + l16][quad * 8];
        }
        #pragma unroll
        for (int ni = 0; ni < 4; ++ni) {
            bh[ni].u = *(const uint4*)&BsH[wn + ni * 16 + l16][quad * 8];
            bm[ni].u = *(const uint4*)&BsM[wn + ni * 16 + l16][quad * 8];
            bl[ni].u = *(const uint4*)&BsL[wn + ni * 16 + l16][quad * 8];
        }

        #pragma unroll
        for (int mi = 0; mi < 4; ++mi)
            #pragma unroll
            for (int ni = 0; ni < 4; ++ni) {
                acc[mi][ni] = __builtin_amdgcn_mfma_f32_16x16x32_bf16(al[mi].b, bh[ni].b, acc[mi][ni], 0, 0, 0);
                acc[mi][ni] = __builtin_amdgcn_mfma_f32_16x16x32_bf16(ah[mi].b, bl[ni].b, acc[mi][ni], 0, 0, 0);
                acc[mi][ni] = __builtin_amdgcn_mfma_f32_16x16x32_bf16(am[mi].b, bm[ni].b, acc[mi][ni], 0, 0, 0);
                acc[mi][ni] = __builtin_amdgcn_mfma_f32_16x16x32_bf16(am[mi].b, bh[ni].b, acc[mi][ni], 0, 0, 0);
                acc[mi][ni] = __builtin_amdgcn_mfma_f32_16x16x32_bf16(ah[mi].b, bm[ni].b, acc[mi][ni], 0, 0, 0);
                acc[mi][ni] = __builtin_amdgcn_mfma_f32_16x16x32_bf16(ah[mi].b, bh[ni].b, acc[mi][ni], 0, 0, 0);
            }
        __syncthreads();
    }

    #pragma unroll
    for (int ni = 0; ni < 4; ++ni) {
        int col = n0 + wn + ni * 16 + l16;
        float bv = biasf[col];
        #pragma unroll
        for (int mi = 0; mi < 4; ++mi) {
            int row = m0 + wm + mi * 16 + quad * 4;
            #pragma unroll
            for (int r = 0; r < 4; ++r)
                M[(size_t)(row + r) * N + col] = acc[mi][ni][r] + bv;
        }
    }
}

// ---------------------------------------------------------------------------
// Kernel 2: symmetrize + reg*I, fp64 Householder tridiag (LDS matrix,
// double2/b128 traffic, pitch 66). Known 294 us.
// ---------------------------------------------------------------------------
__global__ __launch_bounds__(64) void tridiag_kernel(const float* __restrict__ M,
                                                     const float* __restrict__ regf,
                                                     double* __restrict__ trid)
{
    __shared__ __align__(16) double A[64][66];
    __shared__ __align__(16) double ubuf[64];
    __shared__ __align__(16) double wbuf[64];
    __shared__ double ebuf[64];

    int g = blockIdx.x;
    int t = threadIdx.x;
    const float* Mg = M + (size_t)g * 4096;

    for (int r = 0; r < 64; ++r)
        A[r][t] = (double)Mg[r * 64 + t];
    __syncthreads();

    double regv = (double)regf[0];
    for (int j = t + 1; j < 64; ++j) {
        double s = 0.5 * (A[t][j] + A[j][t]);
        A[t][j] = s;
        A[j][t] = s;
    }
    A[t][t] += regv;
    __syncthreads();

    for (int k = 0; k < 62; ++k) {
        double x = (t > k) ? A[t][k] : 0.0;
        double sigma = wsum(x * x);
        double x1 = __shfl(x, k + 1, 64);
        double alpha = 0.0;
        if (sigma > 1e-300) {
            double sq = sqrt(sigma);
            alpha = (x1 >= 0.0) ? -sq : sq;
            double Kh = sigma - x1 * alpha;    // u^T u / 2 > 0
            double u = (t == k + 1) ? (x - alpha) : x;
            ubuf[t] = u;
            __syncthreads();

            int je = (k + 1) & ~1;
            double px = 0.0, py = 0.0;
            #pragma unroll 4
            for (int j = je; j < 64; j += 2) {
                double2 av = *(const double2*)&A[t][j];
                double2 uv = *(const double2*)&ubuf[j];
                px += av.x * uv.x;
                py += av.y * uv.y;
            }
            double p = (t > k) ? (px + py) / Kh : 0.0;

            double c = wsum(u * p) / (2.0 * Kh);
            double w = p - c * u;
            wbuf[t] = w;
            __syncthreads();

            if (t > k) {
                #pragma unroll 4
                for (int j = je; j < 64; j += 2) {
                    double2 av = *(double2*)&A[t][j];
                    double2 uv = *(const double2*)&ubuf[j];
                    double2 wv = *(const double2*)&wbuf[j];
                    av.x -= u * wv.x + w * uv.x;
                    av.y -= u * wv.y + w * uv.y;
                    *(double2*)&A[t][j] = av;
                }
            }
        }
        if (t == 0) ebuf[k] = alpha;
        __syncthreads();
    }

    if (t == 0) { ebuf[62] = A[63][62]; ebuf[63] = 0.0; }
    __syncthreads();

    double* tg = trid + (size_t)g * 128;
    tg[t]      = A[t][t];
    tg[64 + t] = ebuf[t];
}

// ---------------------------------------------------------------------------
// Kernel 3: bisection (Sturm sign-count) per eigenvalue; descending + log-clip.
// ---------------------------------------------------------------------------
__global__ __launch_bounds__(64) void bisect_kernel(const double* __restrict__ trid,
                                                    float* __restrict__ out)
{
    __shared__ double dd[64];
    __shared__ double e2[64];
    __shared__ double ea[64];

    int g = blockIdx.x;
    int t = threadIdx.x;
    const double* tg = trid + (size_t)g * 128;

    double dv = tg[t];
    double ev = tg[64 + t];
    dd[t] = dv;
    ea[t] = fabs(ev);
    e2[t] = ev * ev;
    __syncthreads();

    double el  = (t > 0) ? ea[t - 1] : 0.0;
    double er  = (t < 63) ? ea[t] : 0.0;
    double rad = el + er;
    double lo = wmin(dv - rad);
    double hi = wmax(dv + rad);
    double mid0 = 0.5 * (lo + hi);
    double half = (0.5 * (hi - lo) + 1e-12) * 1.0000001;
    double a = mid0 - half;
    double b = mid0 + half;

    for (int it = 0; it < 34; ++it) {
        double xm = 0.5 * (a + b);
        double pm = 1.0;
        double p  = dd[0] - xm;
        int cnt = (p < 0.0);
        #pragma unroll
        for (int i = 1; i < 64; ++i) {
            double pi = (dd[i] - xm) * p - e2[i - 1] * pm;
            cnt += ((pi < 0.0) != (p < 0.0));
            double ap = fabs(pi);
            double s = (ap > 1e150) ? 1e-150 : ((ap < 1e-150) ? 1e150 : 1.0);
            pm = p * s;
            p  = pi * s;
        }
        if (cnt > t) b = xm; else a = xm;
    }

    double lam = 0.5 * (a + b);
    double v = fmax(lam, 1e-8);
    out[(size_t)g * 64 + (63 - t)] = (float)log(v);
}

// ---------------------------------------------------------------------------
extern "C" void kernel_launch(void* const* d_in, const int* in_sizes, int n_in,
                              void* d_out, int out_size, void* d_ws, size_t ws_size,
                              hipStream_t stream)
{
    const float* X    = (const float*)d_in[0]; // [2048,2048] fp32
    const float* Wt   = (const float*)d_in[1]; // [4096,2048] fp32
    const float* bias = (const float*)d_in[2]; // [4096] fp32
    const float* regp = (const float*)d_in[3]; // [1] fp32

    char* w = (char*)d_ws;
    float*  M    = (float*)w;                        // 32 MB
    double* trid = (double*)(w + 33554432);          // 2 MB
    float* out = (float*)d_out;                      // [2048,64] fp32

    const size_t NEED_PLANES = 111149056ull;
    if (ws_size >= NEED_PLANES) {
        unsigned short* Xh = (unsigned short*)(w + 35651584);
        unsigned short* Xm = (unsigned short*)(w + 44040192);
        unsigned short* Xl = (unsigned short*)(w + 52428800);
        unsigned short* Wh = (unsigned short*)(w + 60817408);
        unsigned short* Wm = (unsigned short*)(w + 77594624);
        unsigned short* Wl = (unsigned short*)(w + 94371840);
        split_kernel<<<dim3(12288), dim3(256), 0, stream>>>(X, Wt, Xh, Xm, Xl, Wh, Wm, Wl);
        gemm_pipe<<<dim3(32, 16), dim3(256), 0, stream>>>(
            Xh, Xm, Xl, Wh, Wm, Wl, bias, M);
    } else {
        gemm_bt<<<dim3(32, 16), dim3(256), 0, stream>>>(X, Wt, bias, M);
    }
    tridiag_kernel<<<dim3(2048), dim3(64), 0, stream>>>(M, regp, trid);
    bisect_kernel<<<dim3(2048), dim3(64), 0, stream>>>(trid, out);
}

// Round 8
// 740.898 us; speedup vs baseline: 1.3981x; 1.3981x over previous
//
#include <hip/hip_runtime.h>

typedef __bf16 bf16x8 __attribute__((ext_vector_type(8)));
typedef float f32x4 __attribute__((ext_vector_type(4)));

union U8 { uint4 u; bf16x8 b; };

__device__ inline float bf16f(unsigned short h) {
    return __uint_as_float(((unsigned)h) << 16);
}

__device__ inline unsigned short f32_to_bf16_rn(float f) {
    unsigned u = __float_as_uint(f);
    unsigned rounding = 0x7FFFu + ((u >> 16) & 1u);
    u += rounding;
    return (unsigned short)(u >> 16);
}

__device__ inline double wsum(double v) {
    #pragma unroll
    for (int m = 32; m; m >>= 1) v += __shfl_xor(v, m, 64);
    return v;
}
__device__ inline double wmin(double v) {
    #pragma unroll
    for (int m = 32; m; m >>= 1) v = fmin(v, __shfl_xor(v, m, 64));
    return v;
}
__device__ inline double wmax(double v) {
    #pragma unroll
    for (int m = 32; m; m >>= 1) v = fmax(v, __shfl_xor(v, m, 64));
    return v;
}

#define AS1C(p) ((const __attribute__((address_space(1))) void*)(p))
#define AS3(p)  ((__attribute__((address_space(3))) void*)(p))

// ---------------------------------------------------------------------------
// Kernel 0: pre-split fp32 -> 3 bf16 planes (h+m+l) for X and W.
// ---------------------------------------------------------------------------
__global__ __launch_bounds__(256) void split_kernel(
    const float* __restrict__ X, const float* __restrict__ W,
    unsigned short* __restrict__ Xh, unsigned short* __restrict__ Xm, unsigned short* __restrict__ Xl,
    unsigned short* __restrict__ Wh, unsigned short* __restrict__ Wm, unsigned short* __restrict__ Wl)
{
    size_t i4 = (size_t)blockIdx.x * 256 + threadIdx.x;   // float4 index, total 3145728
    const float* src; unsigned short *ph, *pm, *pl; size_t off4;
    if (i4 < 1048576) { src = X; ph = Xh; pm = Xm; pl = Xl; off4 = i4; }
    else              { src = W; ph = Wh; pm = Wm; pl = Wl; off4 = i4 - 1048576; }

    float4 v = ((const float4*)src)[off4];
    ushort4 h, m, l;
    float r1;
    h.x = f32_to_bf16_rn(v.x); r1 = v.x - bf16f(h.x);
    m.x = f32_to_bf16_rn(r1);  l.x = f32_to_bf16_rn(r1 - bf16f(m.x));
    h.y = f32_to_bf16_rn(v.y); r1 = v.y - bf16f(h.y);
    m.y = f32_to_bf16_rn(r1);  l.y = f32_to_bf16_rn(r1 - bf16f(m.y));
    h.z = f32_to_bf16_rn(v.z); r1 = v.z - bf16f(h.z);
    m.z = f32_to_bf16_rn(r1);  l.z = f32_to_bf16_rn(r1 - bf16f(m.z));
    h.w = f32_to_bf16_rn(v.w); r1 = v.w - bf16f(h.w);
    m.w = f32_to_bf16_rn(r1);  l.w = f32_to_bf16_rn(r1 - bf16f(m.w));

    ((ushort4*)ph)[off4] = h;
    ((ushort4*)pm)[off4] = m;
    ((ushort4*)pl)[off4] = l;
}

// ---------------------------------------------------------------------------
// Kernel 1 (v4): 6-plane bf16 GEMM, 128x64 tiles -> 1024 blocks, 36 KB LDS
// -> 4 blocks/CU (16 waves/CU). Single-buffer global_load_lds width-16,
// m97-proven 2-barrier K-loop. 48 MFMA / 9 loads per wave-tile.
// XCD swizzle: each XCD owns a 16(by) x 8(bx) slab for W-panel L2 locality.
// ---------------------------------------------------------------------------
__global__ __launch_bounds__(256) void gemm_64(
    const unsigned short* __restrict__ Xh, const unsigned short* __restrict__ Xm,
    const unsigned short* __restrict__ Xl,
    const unsigned short* __restrict__ Wh, const unsigned short* __restrict__ Wm,
    const unsigned short* __restrict__ Wl,
    const float* __restrict__ biasf, float* __restrict__ M)
{
    const int K = 2048, N = 4096;
    // ushort units: A planes at p*4096 (128x32 each), B planes at 12288+p*2048 (64x32)
    __shared__ unsigned short S[18432];   // 36 KB

    int tid  = threadIdx.x;
    int id   = blockIdx.x;                 // 0..1023
    int c    = id & 7;                     // XCD (hw round-robins id%8)
    int sid  = id >> 3;                    // 0..127
    int bx   = c * 8 + (sid & 7);          // 0..63
    int by   = sid >> 3;                   // 0..15
    int m0   = by * 128;
    int n0   = bx * 64;

    int wave = tid >> 6;
    int lane = tid & 63;
    int l16  = lane & 15;
    int quad = lane >> 4;
    int wm   = wave * 32;

    const unsigned short* gpA[3];
    const unsigned short* gpB[3];
    gpA[0] = Xh + (size_t)m0 * K;
    gpA[1] = Xm + (size_t)m0 * K;
    gpA[2] = Xl + (size_t)m0 * K;
    gpB[0] = Wh + (size_t)n0 * K;
    gpB[1] = Wm + (size_t)n0 * K;
    gpB[2] = Wl + (size_t)n0 * K;

    int rA = lane >> 2;              // 0..15
    int cA = (lane & 3) << 3;        // ushort col offset 0,8,16,24

    f32x4 acc[2][4];
    #pragma unroll
    for (int mi = 0; mi < 2; ++mi)
        #pragma unroll
        for (int ni = 0; ni < 4; ++ni)
            acc[mi][ni] = f32x4{0.f, 0.f, 0.f, 0.f};

    for (int k0 = 0; k0 < K; k0 += 32) {
        __syncthreads();   // prior tile's ds_reads done before overwrite
        #pragma unroll
        for (int p = 0; p < 3; ++p) {
            #pragma unroll
            for (int q = 0; q < 2; ++q) {
                const unsigned short* g = gpA[p] + (size_t)(32 * wave + 16 * q + rA) * K + k0 + cA;
                char* l = (char*)S + p * 8192 + wave * 2048 + q * 1024;
                __builtin_amdgcn_global_load_lds(AS1C(g), AS3(l), 16, 0, 0);
            }
            {
                const unsigned short* g = gpB[p] + (size_t)(16 * wave + rA) * K + k0 + cA;
                char* l = (char*)S + 24576 + p * 4096 + wave * 1024;
                __builtin_amdgcn_global_load_lds(AS1C(g), AS3(l), 16, 0, 0);
            }
        }
        __syncthreads();   // staged tile visible

        U8 ah[2], am[2], al[2], bh[4], bm[4], bl[4];
        #pragma unroll
        for (int mi = 0; mi < 2; ++mi) {
            int ro = (wm + mi * 16 + l16) * 32 + quad * 8;
            ah[mi].u = *(const uint4*)&S[ro];
            am[mi].u = *(const uint4*)&S[4096 + ro];
            al[mi].u = *(const uint4*)&S[8192 + ro];
        }
        #pragma unroll
        for (int ni = 0; ni < 4; ++ni) {
            int ro = (ni * 16 + l16) * 32 + quad * 8;
            bh[ni].u = *(const uint4*)&S[12288 + ro];
            bm[ni].u = *(const uint4*)&S[14336 + ro];
            bl[ni].u = *(const uint4*)&S[16384 + ro];
        }

        #pragma unroll
        for (int mi = 0; mi < 2; ++mi)
            #pragma unroll
            for (int ni = 0; ni < 4; ++ni) {
                acc[mi][ni] = __builtin_amdgcn_mfma_f32_16x16x32_bf16(
                    al[mi].b, bh[ni].b, acc[mi][ni], 0, 0, 0);
                acc[mi][ni] = __builtin_amdgcn_mfma_f32_16x16x32_bf16(
                    ah[mi].b, bl[ni].b, acc[mi][ni], 0, 0, 0);
                acc[mi][ni] = __builtin_amdgcn_mfma_f32_16x16x32_bf16(
                    am[mi].b, bm[ni].b, acc[mi][ni], 0, 0, 0);
                acc[mi][ni] = __builtin_amdgcn_mfma_f32_16x16x32_bf16(
                    am[mi].b, bh[ni].b, acc[mi][ni], 0, 0, 0);
                acc[mi][ni] = __builtin_amdgcn_mfma_f32_16x16x32_bf16(
                    ah[mi].b, bm[ni].b, acc[mi][ni], 0, 0, 0);
                acc[mi][ni] = __builtin_amdgcn_mfma_f32_16x16x32_bf16(
                    ah[mi].b, bh[ni].b, acc[mi][ni], 0, 0, 0);
            }
    }

    // epilogue: C/D layout col = lane&15, row = quad*4 + reg
    #pragma unroll
    for (int ni = 0; ni < 4; ++ni) {
        int col = n0 + ni * 16 + l16;
        float bv = biasf[col];
        #pragma unroll
        for (int mi = 0; mi < 2; ++mi) {
            int row = m0 + wm + mi * 16 + quad * 4;
            #pragma unroll
            for (int r = 0; r < 4; ++r)
                M[(size_t)(row + r) * N + col] = acc[mi][ni][r] + bv;
        }
    }
}

// ---------------------------------------------------------------------------
// Kernel 1-fallback: round-3 in-kernel split GEMM (used only if ws too small).
// ---------------------------------------------------------------------------
__global__ __launch_bounds__(256) void gemm_bt(const float* __restrict__ Xf,
                                               const float* __restrict__ Wf,
                                               const float* __restrict__ biasf,
                                               float* __restrict__ M)
{
    const int K = 2048, N = 4096;
    __shared__ unsigned short AsH[128][32];
    __shared__ unsigned short AsM[128][32];
    __shared__ unsigned short AsL[128][32];
    __shared__ unsigned short BsH[128][32];
    __shared__ unsigned short BsM[128][32];
    __shared__ unsigned short BsL[128][32];

    int tid  = threadIdx.x;
    int m0   = blockIdx.y * 128;
    int n0   = blockIdx.x * 128;
    int wid  = tid >> 6;
    int lane = tid & 63;
    int wm   = (wid >> 1) * 64;
    int wn   = (wid & 1) * 64;
    int l16  = lane & 15;
    int quad = lane >> 4;

    f32x4 acc[4][4];
    #pragma unroll
    for (int mi = 0; mi < 4; ++mi)
        #pragma unroll
        for (int ni = 0; ni < 4; ++ni)
            acc[mi][ni] = f32x4{0.f, 0.f, 0.f, 0.f};

    for (int k0 = 0; k0 < K; k0 += 32) {
        #pragma unroll
        for (int s = 0; s < 4; ++s) {
            int c  = tid + s * 256;
            int r  = c >> 3;
            int kc = (c & 7) << 2;
            {
                float4 v = *(const float4*)&Xf[(size_t)(m0 + r) * K + k0 + kc];
                ushort4 h, mm_, l; float r1;
                h.x = f32_to_bf16_rn(v.x); r1 = v.x - bf16f(h.x);
                mm_.x = f32_to_bf16_rn(r1); l.x = f32_to_bf16_rn(r1 - bf16f(mm_.x));
                h.y = f32_to_bf16_rn(v.y); r1 = v.y - bf16f(h.y);
                mm_.y = f32_to_bf16_rn(r1); l.y = f32_to_bf16_rn(r1 - bf16f(mm_.y));
                h.z = f32_to_bf16_rn(v.z); r1 = v.z - bf16f(h.z);
                mm_.z = f32_to_bf16_rn(r1); l.z = f32_to_bf16_rn(r1 - bf16f(mm_.z));
                h.w = f32_to_bf16_rn(v.w); r1 = v.w - bf16f(h.w);
                mm_.w = f32_to_bf16_rn(r1); l.w = f32_to_bf16_rn(r1 - bf16f(mm_.w));
                *(ushort4*)&AsH[r][kc] = h; *(ushort4*)&AsM[r][kc] = mm_; *(ushort4*)&AsL[r][kc] = l;
            }
            {
                float4 v = *(const float4*)&Wf[(size_t)(n0 + r) * K + k0 + kc];
                ushort4 h, mm_, l; float r1;
                h.x = f32_to_bf16_rn(v.x); r1 = v.x - bf16f(h.x);
                mm_.x = f32_to_bf16_rn(r1); l.x = f32_to_bf16_rn(r1 - bf16f(mm_.x));
                h.y = f32_to_bf16_rn(v.y); r1 = v.y - bf16f(h.y);
                mm_.y = f32_to_bf16_rn(r1); l.y = f32_to_bf16_rn(r1 - bf16f(mm_.y));
                h.z = f32_to_bf16_rn(v.z); r1 = v.z - bf16f(h.z);
                mm_.z = f32_to_bf16_rn(r1); l.z = f32_to_bf16_rn(r1 - bf16f(mm_.z));
                h.w = f32_to_bf16_rn(v.w); r1 = v.w - bf16f(h.w);
                mm_.w = f32_to_bf16_rn(r1); l.w = f32_to_bf16_rn(r1 - bf16f(mm_.w));
                *(ushort4*)&BsH[r][kc] = h; *(ushort4*)&BsM[r][kc] = mm_; *(ushort4*)&BsL[r][kc] = l;
            }
        }
        __syncthreads();

        U8 ah[4], am[4], al[4], bh[4], bm[4], bl[4];
        #pragma unroll
        for (int mi = 0; mi < 4; ++mi) {
            ah[mi].u = *(const uint4*)&AsH[wm + mi * 16 + l16][quad * 8];
            am[mi].u = *(const uint4*)&AsM[wm + mi * 16 + l16][quad * 8];
            al[mi].u = *(const uint4*)&AsL[wm + mi * 16 + l16][quad * 8];
        }
        #pragma unroll
        for (int ni = 0; ni < 4; ++ni) {
            bh[ni].u = *(const uint4*)&BsH[wn + ni * 16 + l16][quad * 8];
            bm[ni].u = *(const uint4*)&BsM[wn + ni * 16 + l16][quad * 8];
            bl[ni].u = *(const uint4*)&BsL[wn + ni * 16 + l16][quad * 8];
        }

        #pragma unroll
        for (int mi = 0; mi < 4; ++mi)
            #pragma unroll
            for (int ni = 0; ni < 4; ++ni) {
                acc[mi][ni] = __builtin_amdgcn_mfma_f32_16x16x32_bf16(al[mi].b, bh[ni].b, acc[mi][ni], 0, 0, 0);
                acc[mi][ni] = __builtin_amdgcn_mfma_f32_16x16x32_bf16(ah[mi].b, bl[ni].b, acc[mi][ni], 0, 0, 0);
                acc[mi][ni] = __builtin_amdgcn_mfma_f32_16x16x32_bf16(am[mi].b, bm[ni].b, acc[mi][ni], 0, 0, 0);
                acc[mi][ni] = __builtin_amdgcn_mfma_f32_16x16x32_bf16(am[mi].b, bh[ni].b, acc[mi][ni], 0, 0, 0);
                acc[mi][ni] = __builtin_amdgcn_mfma_f32_16x16x32_bf16(ah[mi].b, bm[ni].b, acc[mi][ni], 0, 0, 0);
                acc[mi][ni] = __builtin_amdgcn_mfma_f32_16x16x32_bf16(ah[mi].b, bh[ni].b, acc[mi][ni], 0, 0, 0);
            }
        __syncthreads();
    }

    #pragma unroll
    for (int ni = 0; ni < 4; ++ni) {
        int col = n0 + wn + ni * 16 + l16;
        float bv = biasf[col];
        #pragma unroll
        for (int mi = 0; mi < 4; ++mi) {
            int row = m0 + wm + mi * 16 + quad * 4;
            #pragma unroll
            for (int r = 0; r < 4; ++r)
                M[(size_t)(row + r) * N + col] = acc[mi][ni][r] + bv;
        }
    }
}

// ---------------------------------------------------------------------------
// Kernel 2: symmetrize + reg*I, fp64 Householder tridiag (LDS matrix,
// double2/b128 traffic, pitch 66). Known 294 us.
// ---------------------------------------------------------------------------
__global__ __launch_bounds__(64) void tridiag_kernel(const float* __restrict__ M,
                                                     const float* __restrict__ regf,
                                                     double* __restrict__ trid)
{
    __shared__ __align__(16) double A[64][66];
    __shared__ __align__(16) double ubuf[64];
    __shared__ __align__(16) double wbuf[64];
    __shared__ double ebuf[64];

    int g = blockIdx.x;
    int t = threadIdx.x;
    const float* Mg = M + (size_t)g * 4096;

    for (int r = 0; r < 64; ++r)
        A[r][t] = (double)Mg[r * 64 + t];
    __syncthreads();

    double regv = (double)regf[0];
    for (int j = t + 1; j < 64; ++j) {
        double s = 0.5 * (A[t][j] + A[j][t]);
        A[t][j] = s;
        A[j][t] = s;
    }
    A[t][t] += regv;
    __syncthreads();

    for (int k = 0; k < 62; ++k) {
        double x = (t > k) ? A[t][k] : 0.0;
        double sigma = wsum(x * x);
        double x1 = __shfl(x, k + 1, 64);
        double alpha = 0.0;
        if (sigma > 1e-300) {
            double sq = sqrt(sigma);
            alpha = (x1 >= 0.0) ? -sq : sq;
            double Kh = sigma - x1 * alpha;    // u^T u / 2 > 0
            double u = (t == k + 1) ? (x - alpha) : x;
            ubuf[t] = u;
            __syncthreads();

            int je = (k + 1) & ~1;
            double px = 0.0, py = 0.0;
            #pragma unroll 4
            for (int j = je; j < 64; j += 2) {
                double2 av = *(const double2*)&A[t][j];
                double2 uv = *(const double2*)&ubuf[j];
                px += av.x * uv.x;
                py += av.y * uv.y;
            }
            double p = (t > k) ? (px + py) / Kh : 0.0;

            double c = wsum(u * p) / (2.0 * Kh);
            double w = p - c * u;
            wbuf[t] = w;
            __syncthreads();

            if (t > k) {
                #pragma unroll 4
                for (int j = je; j < 64; j += 2) {
                    double2 av = *(double2*)&A[t][j];
                    double2 uv = *(const double2*)&ubuf[j];
                    double2 wv = *(const double2*)&wbuf[j];
                    av.x -= u * wv.x + w * uv.x;
                    av.y -= u * wv.y + w * uv.y;
                    *(double2*)&A[t][j] = av;
                }
            }
        }
        if (t == 0) ebuf[k] = alpha;
        __syncthreads();
    }

    if (t == 0) { ebuf[62] = A[63][62]; ebuf[63] = 0.0; }
    __syncthreads();

    double* tg = trid + (size_t)g * 128;
    tg[t]      = A[t][t];
    tg[64 + t] = ebuf[t];
}

// ---------------------------------------------------------------------------
// Kernel 3: bisection (Sturm sign-count) per eigenvalue; descending + log-clip.
// ---------------------------------------------------------------------------
__global__ __launch_bounds__(64) void bisect_kernel(const double* __restrict__ trid,
                                                    float* __restrict__ out)
{
    __shared__ double dd[64];
    __shared__ double e2[64];
    __shared__ double ea[64];

    int g = blockIdx.x;
    int t = threadIdx.x;
    const double* tg = trid + (size_t)g * 128;

    double dv = tg[t];
    double ev = tg[64 + t];
    dd[t] = dv;
    ea[t] = fabs(ev);
    e2[t] = ev * ev;
    __syncthreads();

    double el  = (t > 0) ? ea[t - 1] : 0.0;
    double er  = (t < 63) ? ea[t] : 0.0;
    double rad = el + er;
    double lo = wmin(dv - rad);
    double hi = wmax(dv + rad);
    double mid0 = 0.5 * (lo + hi);
    double half = (0.5 * (hi - lo) + 1e-12) * 1.0000001;
    double a = mid0 - half;
    double b = mid0 + half;

    for (int it = 0; it < 34; ++it) {
        double xm = 0.5 * (a + b);
        double pm = 1.0;
        double p  = dd[0] - xm;
        int cnt = (p < 0.0);
        #pragma unroll
        for (int i = 1; i < 64; ++i) {
            double pi = (dd[i] - xm) * p - e2[i - 1] * pm;
            cnt += ((pi < 0.0) != (p < 0.0));
            double ap = fabs(pi);
            double s = (ap > 1e150) ? 1e-150 : ((ap < 1e-150) ? 1e150 : 1.0);
            pm = p * s;
            p  = pi * s;
        }
        if (cnt > t) b = xm; else a = xm;
    }

    double lam = 0.5 * (a + b);
    double v = fmax(lam, 1e-8);
    out[(size_t)g * 64 + (63 - t)] = (float)log(v);
}

// ---------------------------------------------------------------------------
extern "C" void kernel_launch(void* const* d_in, const int* in_sizes, int n_in,
                              void* d_out, int out_size, void* d_ws, size_t ws_size,
                              hipStream_t stream)
{
    const float* X    = (const float*)d_in[0]; // [2048,2048] fp32
    const float* Wt   = (const float*)d_in[1]; // [4096,2048] fp32
    const float* bias = (const float*)d_in[2]; // [4096] fp32
    const float* regp = (const float*)d_in[3]; // [1] fp32

    char* w = (char*)d_ws;
    float*  M    = (float*)w;                        // 32 MB
    double* trid = (double*)(w + 33554432);          // 2 MB
    float* out = (float*)d_out;                      // [2048,64] fp32

    const size_t NEED_PLANES = 111149056ull;
    if (ws_size >= NEED_PLANES) {
        unsigned short* Xh = (unsigned short*)(w + 35651584);
        unsigned short* Xm = (unsigned short*)(w + 44040192);
        unsigned short* Xl = (unsigned short*)(w + 52428800);
        unsigned short* Wh = (unsigned short*)(w + 60817408);
        unsigned short* Wm = (unsigned short*)(w + 77594624);
        unsigned short* Wl = (unsigned short*)(w + 94371840);
        split_kernel<<<dim3(12288), dim3(256), 0, stream>>>(X, Wt, Xh, Xm, Xl, Wh, Wm, Wl);
        gemm_64<<<dim3(1024), dim3(256), 0, stream>>>(
            Xh, Xm, Xl, Wh, Wm, Wl, bias, M);
    } else {
        gemm_bt<<<dim3(32, 16), dim3(256), 0, stream>>>(X, Wt, bias, M);
    }
    tridiag_kernel<<<dim3(2048), dim3(64), 0, stream>>>(M, regp, trid);
    bisect_kernel<<<dim3(2048), dim3(64), 0, stream>>>(trid, out);
}

// Round 9
// 728.404 us; speedup vs baseline: 1.4220x; 1.0172x over previous
//
#include <hip/hip_runtime.h>

typedef __bf16 bf16x8 __attribute__((ext_vector_type(8)));
typedef float f32x4 __attribute__((ext_vector_type(4)));

union U8 { uint4 u; bf16x8 b; };

__device__ inline float bf16f(unsigned short h) {
    return __uint_as_float(((unsigned)h) << 16);
}

__device__ inline unsigned short f32_to_bf16_rn(float f) {
    unsigned u = __float_as_uint(f);
    unsigned rounding = 0x7FFFu + ((u >> 16) & 1u);
    u += rounding;
    return (unsigned short)(u >> 16);
}

__device__ inline double wsum(double v) {
    #pragma unroll
    for (int m = 32; m; m >>= 1) v += __shfl_xor(v, m, 64);
    return v;
}
__device__ inline double wmin(double v) {
    #pragma unroll
    for (int m = 32; m; m >>= 1) v = fmin(v, __shfl_xor(v, m, 64));
    return v;
}
__device__ inline double wmax(double v) {
    #pragma unroll
    for (int m = 32; m; m >>= 1) v = fmax(v, __shfl_xor(v, m, 64));
    return v;
}

#define AS1C(p) ((const __attribute__((address_space(1))) void*)(p))
#define AS3(p)  ((__attribute__((address_space(3))) void*)(p))

// ---------------------------------------------------------------------------
// Kernel 0: pre-split fp32 -> 3 bf16 planes (h+m+l) for X and W.
// ---------------------------------------------------------------------------
__global__ __launch_bounds__(256) void split_kernel(
    const float* __restrict__ X, const float* __restrict__ W,
    unsigned short* __restrict__ Xh, unsigned short* __restrict__ Xm, unsigned short* __restrict__ Xl,
    unsigned short* __restrict__ Wh, unsigned short* __restrict__ Wm, unsigned short* __restrict__ Wl)
{
    size_t i4 = (size_t)blockIdx.x * 256 + threadIdx.x;   // float4 index, total 3145728
    const float* src; unsigned short *ph, *pm, *pl; size_t off4;
    if (i4 < 1048576) { src = X; ph = Xh; pm = Xm; pl = Xl; off4 = i4; }
    else              { src = W; ph = Wh; pm = Wm; pl = Wl; off4 = i4 - 1048576; }

    float4 v = ((const float4*)src)[off4];
    ushort4 h, m, l;
    float r1;
    h.x = f32_to_bf16_rn(v.x); r1 = v.x - bf16f(h.x);
    m.x = f32_to_bf16_rn(r1);  l.x = f32_to_bf16_rn(r1 - bf16f(m.x));
    h.y = f32_to_bf16_rn(v.y); r1 = v.y - bf16f(h.y);
    m.y = f32_to_bf16_rn(r1);  l.y = f32_to_bf16_rn(r1 - bf16f(m.y));
    h.z = f32_to_bf16_rn(v.z); r1 = v.z - bf16f(h.z);
    m.z = f32_to_bf16_rn(r1);  l.z = f32_to_bf16_rn(r1 - bf16f(m.z));
    h.w = f32_to_bf16_rn(v.w); r1 = v.w - bf16f(h.w);
    m.w = f32_to_bf16_rn(r1);  l.w = f32_to_bf16_rn(r1 - bf16f(m.w));

    ((ushort4*)ph)[off4] = h;
    ((ushort4*)pm)[off4] = m;
    ((ushort4*)pl)[off4] = l;
}

// ---------------------------------------------------------------------------
// Kernel 1 (v4): 6-plane bf16 GEMM, 128x64 tiles -> 1024 blocks, 36 KB LDS
// -> 4 blocks/CU. Single-buffer global_load_lds width-16, 2-barrier K-loop.
// ---------------------------------------------------------------------------
__global__ __launch_bounds__(256) void gemm_64(
    const unsigned short* __restrict__ Xh, const unsigned short* __restrict__ Xm,
    const unsigned short* __restrict__ Xl,
    const unsigned short* __restrict__ Wh, const unsigned short* __restrict__ Wm,
    const unsigned short* __restrict__ Wl,
    const float* __restrict__ biasf, float* __restrict__ M)
{
    const int K = 2048, N = 4096;
    __shared__ unsigned short S[18432];   // 36 KB

    int tid  = threadIdx.x;
    int id   = blockIdx.x;                 // 0..1023
    int c    = id & 7;                     // XCD (hw round-robins id%8)
    int sid  = id >> 3;                    // 0..127
    int bx   = c * 8 + (sid & 7);          // 0..63
    int by   = sid >> 3;                   // 0..15
    int m0   = by * 128;
    int n0   = bx * 64;

    int wave = tid >> 6;
    int lane = tid & 63;
    int l16  = lane & 15;
    int quad = lane >> 4;
    int wm   = wave * 32;

    const unsigned short* gpA[3];
    const unsigned short* gpB[3];
    gpA[0] = Xh + (size_t)m0 * K;
    gpA[1] = Xm + (size_t)m0 * K;
    gpA[2] = Xl + (size_t)m0 * K;
    gpB[0] = Wh + (size_t)n0 * K;
    gpB[1] = Wm + (size_t)n0 * K;
    gpB[2] = Wl + (size_t)n0 * K;

    int rA = lane >> 2;              // 0..15
    int cA = (lane & 3) << 3;        // ushort col offset 0,8,16,24

    f32x4 acc[2][4];
    #pragma unroll
    for (int mi = 0; mi < 2; ++mi)
        #pragma unroll
        for (int ni = 0; ni < 4; ++ni)
            acc[mi][ni] = f32x4{0.f, 0.f, 0.f, 0.f};

    for (int k0 = 0; k0 < K; k0 += 32) {
        __syncthreads();
        #pragma unroll
        for (int p = 0; p < 3; ++p) {
            #pragma unroll
            for (int q = 0; q < 2; ++q) {
                const unsigned short* g = gpA[p] + (size_t)(32 * wave + 16 * q + rA) * K + k0 + cA;
                char* l = (char*)S + p * 8192 + wave * 2048 + q * 1024;
                __builtin_amdgcn_global_load_lds(AS1C(g), AS3(l), 16, 0, 0);
            }
            {
                const unsigned short* g = gpB[p] + (size_t)(16 * wave + rA) * K + k0 + cA;
                char* l = (char*)S + 24576 + p * 4096 + wave * 1024;
                __builtin_amdgcn_global_load_lds(AS1C(g), AS3(l), 16, 0, 0);
            }
        }
        __syncthreads();

        U8 ah[2], am[2], al[2], bh[4], bm[4], bl[4];
        #pragma unroll
        for (int mi = 0; mi < 2; ++mi) {
            int ro = (wm + mi * 16 + l16) * 32 + quad * 8;
            ah[mi].u = *(const uint4*)&S[ro];
            am[mi].u = *(const uint4*)&S[4096 + ro];
            al[mi].u = *(const uint4*)&S[8192 + ro];
        }
        #pragma unroll
        for (int ni = 0; ni < 4; ++ni) {
            int ro = (ni * 16 + l16) * 32 + quad * 8;
            bh[ni].u = *(const uint4*)&S[12288 + ro];
            bm[ni].u = *(const uint4*)&S[14336 + ro];
            bl[ni].u = *(const uint4*)&S[16384 + ro];
        }

        #pragma unroll
        for (int mi = 0; mi < 2; ++mi)
            #pragma unroll
            for (int ni = 0; ni < 4; ++ni) {
                acc[mi][ni] = __builtin_amdgcn_mfma_f32_16x16x32_bf16(
                    al[mi].b, bh[ni].b, acc[mi][ni], 0, 0, 0);
                acc[mi][ni] = __builtin_amdgcn_mfma_f32_16x16x32_bf16(
                    ah[mi].b, bl[ni].b, acc[mi][ni], 0, 0, 0);
                acc[mi][ni] = __builtin_amdgcn_mfma_f32_16x16x32_bf16(
                    am[mi].b, bm[ni].b, acc[mi][ni], 0, 0, 0);
                acc[mi][ni] = __builtin_amdgcn_mfma_f32_16x16x32_bf16(
                    am[mi].b, bh[ni].b, acc[mi][ni], 0, 0, 0);
                acc[mi][ni] = __builtin_amdgcn_mfma_f32_16x16x32_bf16(
                    ah[mi].b, bm[ni].b, acc[mi][ni], 0, 0, 0);
                acc[mi][ni] = __builtin_amdgcn_mfma_f32_16x16x32_bf16(
                    ah[mi].b, bh[ni].b, acc[mi][ni], 0, 0, 0);
            }
    }

    #pragma unroll
    for (int ni = 0; ni < 4; ++ni) {
        int col = n0 + ni * 16 + l16;
        float bv = biasf[col];
        #pragma unroll
        for (int mi = 0; mi < 2; ++mi) {
            int row = m0 + wm + mi * 16 + quad * 4;
            #pragma unroll
            for (int r = 0; r < 4; ++r)
                M[(size_t)(row + r) * N + col] = acc[mi][ni][r] + bv;
        }
    }
}

// ---------------------------------------------------------------------------
// Kernel 1-fallback: round-3 in-kernel split GEMM (used only if ws too small).
// ---------------------------------------------------------------------------
__global__ __launch_bounds__(256) void gemm_bt(const float* __restrict__ Xf,
                                               const float* __restrict__ Wf,
                                               const float* __restrict__ biasf,
                                               float* __restrict__ M)
{
    const int K = 2048, N = 4096;
    __shared__ unsigned short AsH[128][32];
    __shared__ unsigned short AsM[128][32];
    __shared__ unsigned short AsL[128][32];
    __shared__ unsigned short BsH[128][32];
    __shared__ unsigned short BsM[128][32];
    __shared__ unsigned short BsL[128][32];

    int tid  = threadIdx.x;
    int m0   = blockIdx.y * 128;
    int n0   = blockIdx.x * 128;
    int wid  = tid >> 6;
    int lane = tid & 63;
    int wm   = (wid >> 1) * 64;
    int wn   = (wid & 1) * 64;
    int l16  = lane & 15;
    int quad = lane >> 4;

    f32x4 acc[4][4];
    #pragma unroll
    for (int mi = 0; mi < 4; ++mi)
        #pragma unroll
        for (int ni = 0; ni < 4; ++ni)
            acc[mi][ni] = f32x4{0.f, 0.f, 0.f, 0.f};

    for (int k0 = 0; k0 < K; k0 += 32) {
        #pragma unroll
        for (int s = 0; s < 4; ++s) {
            int c  = tid + s * 256;
            int r  = c >> 3;
            int kc = (c & 7) << 2;
            {
                float4 v = *(const float4*)&Xf[(size_t)(m0 + r) * K + k0 + kc];
                ushort4 h, mm_, l; float r1;
                h.x = f32_to_bf16_rn(v.x); r1 = v.x - bf16f(h.x);
                mm_.x = f32_to_bf16_rn(r1); l.x = f32_to_bf16_rn(r1 - bf16f(mm_.x));
                h.y = f32_to_bf16_rn(v.y); r1 = v.y - bf16f(h.y);
                mm_.y = f32_to_bf16_rn(r1); l.y = f32_to_bf16_rn(r1 - bf16f(mm_.y));
                h.z = f32_to_bf16_rn(v.z); r1 = v.z - bf16f(h.z);
                mm_.z = f32_to_bf16_rn(r1); l.z = f32_to_bf16_rn(r1 - bf16f(mm_.z));
                h.w = f32_to_bf16_rn(v.w); r1 = v.w - bf16f(h.w);
                mm_.w = f32_to_bf16_rn(r1); l.w = f32_to_bf16_rn(r1 - bf16f(mm_.w));
                *(ushort4*)&AsH[r][kc] = h; *(ushort4*)&AsM[r][kc] = mm_; *(ushort4*)&AsL[r][kc] = l;
            }
            {
                float4 v = *(const float4*)&Wf[(size_t)(n0 + r) * K + k0 + kc];
                ushort4 h, mm_, l; float r1;
                h.x = f32_to_bf16_rn(v.x); r1 = v.x - bf16f(h.x);
                mm_.x = f32_to_bf16_rn(r1); l.x = f32_to_bf16_rn(r1 - bf16f(mm_.x));
                h.y = f32_to_bf16_rn(v.y); r1 = v.y - bf16f(h.y);
                mm_.y = f32_to_bf16_rn(r1); l.y = f32_to_bf16_rn(r1 - bf16f(mm_.y));
                h.z = f32_to_bf16_rn(v.z); r1 = v.z - bf16f(h.z);
                mm_.z = f32_to_bf16_rn(r1); l.z = f32_to_bf16_rn(r1 - bf16f(mm_.z));
                h.w = f32_to_bf16_rn(v.w); r1 = v.w - bf16f(h.w);
                mm_.w = f32_to_bf16_rn(r1); l.w = f32_to_bf16_rn(r1 - bf16f(mm_.w));
                *(ushort4*)&BsH[r][kc] = h; *(ushort4*)&BsM[r][kc] = mm_; *(ushort4*)&BsL[r][kc] = l;
            }
        }
        __syncthreads();

        U8 ah[4], am[4], al[4], bh[4], bm[4], bl[4];
        #pragma unroll
        for (int mi = 0; mi < 4; ++mi) {
            ah[mi].u = *(const uint4*)&AsH[wm + mi * 16 + l16][quad * 8];
            am[mi].u = *(const uint4*)&AsM[wm + mi * 16 + l16][quad * 8];
            al[mi].u = *(const uint4*)&AsL[wm + mi * 16 + l16][quad * 8];
        }
        #pragma unroll
        for (int ni = 0; ni < 4; ++ni) {
            bh[ni].u = *(const uint4*)&BsH[wn + ni * 16 + l16][quad * 8];
            bm[ni].u = *(const uint4*)&BsM[wn + ni * 16 + l16][quad * 8];
            bl[ni].u = *(const uint4*)&BsL[wn + ni * 16 + l16][quad * 8];
        }

        #pragma unroll
        for (int mi = 0; mi < 4; ++mi)
            #pragma unroll
            for (int ni = 0; ni < 4; ++ni) {
                acc[mi][ni] = __builtin_amdgcn_mfma_f32_16x16x32_bf16(al[mi].b, bh[ni].b, acc[mi][ni], 0, 0, 0);
                acc[mi][ni] = __builtin_amdgcn_mfma_f32_16x16x32_bf16(ah[mi].b, bl[ni].b, acc[mi][ni], 0, 0, 0);
                acc[mi][ni] = __builtin_amdgcn_mfma_f32_16x16x32_bf16(am[mi].b, bm[ni].b, acc[mi][ni], 0, 0, 0);
                acc[mi][ni] = __builtin_amdgcn_mfma_f32_16x16x32_bf16(am[mi].b, bh[ni].b, acc[mi][ni], 0, 0, 0);
                acc[mi][ni] = __builtin_amdgcn_mfma_f32_16x16x32_bf16(ah[mi].b, bm[ni].b, acc[mi][ni], 0, 0, 0);
                acc[mi][ni] = __builtin_amdgcn_mfma_f32_16x16x32_bf16(ah[mi].b, bh[ni].b, acc[mi][ni], 0, 0, 0);
            }
        __syncthreads();
    }

    #pragma unroll
    for (int ni = 0; ni < 4; ++ni) {
        int col = n0 + wn + ni * 16 + l16;
        float bv = biasf[col];
        #pragma unroll
        for (int mi = 0; mi < 4; ++mi) {
            int row = m0 + wm + mi * 16 + quad * 4;
            #pragma unroll
            for (int r = 0; r < 4; ++r)
                M[(size_t)(row + r) * N + col] = acc[mi][ni][r] + bv;
        }
    }
}

// ---------------------------------------------------------------------------
// Kernel 2 (v4): fp64 Householder tridiag, row REGISTER-resident with all
// static indices. Key identities: ubuf[j]=wbuf[j]=0 for j<=k, so every inner
// loop is static full-width 0..63; the k-loop stays dynamic (unroll 1), so
// the compiler can register-allocate A[64]. Column k obtained by lane k
// dumping its (final) row to LDS. sigma from lane k's registers + 1 shfl.
// LDS ~20 KB -> 8 blocks/CU = 2 waves/SIMD.
// ---------------------------------------------------------------------------
__global__ __launch_bounds__(64, 2) void tridiag_kernel(const float* __restrict__ M,
                                                        const float* __restrict__ regf,
                                                        double* __restrict__ trid)
{
    __shared__ float Ms[64][65];                       // 16.6 KB staging
    __shared__ __align__(16) double rowb[64];          // column k (= row k dump)
    __shared__ __align__(16) double ubuf[64];
    __shared__ __align__(16) double wbuf[64];
    __shared__ double dbuf[64];
    __shared__ double ebuf[64];

    int g = blockIdx.x;
    int t = threadIdx.x;
    const float* Mg = M + (size_t)g * 4096;

    for (int r = 0; r < 64; ++r)
        Ms[r][t] = Mg[r * 64 + t];                     // coalesced
    __syncthreads();

    double regv = (double)regf[0];
    double A[64];                                      // row t, register-resident
    #pragma unroll
    for (int j = 0; j < 64; ++j)
        A[j] = 0.5 * ((double)Ms[t][j] + (double)Ms[j][t]);
    #pragma unroll
    for (int j = 0; j < 64; ++j)
        A[j] += (j == t) ? regv : 0.0;

    #pragma unroll 1
    for (int k = 0; k < 62; ++k) {
        // lane k's row is final: dump it (it IS column k by symmetry)
        if (t == k) {
            #pragma unroll
            for (int j = 0; j < 32; ++j)
                *(double2*)&rowb[2 * j] = double2{A[2 * j], A[2 * j + 1]};
        }
        __syncthreads();

        // sigma = tail-norm of row k: every lane computes its own tail-norm
        // (static loop), lane k's value is taken.
        double s0 = 0.0, s1 = 0.0;
        #pragma unroll
        for (int j = 0; j < 64; ++j) {
            double aj = (j > k) ? A[j] : 0.0;
            if (j & 1) s1 += aj * aj; else s0 += aj * aj;
        }
        double sigma = __shfl(s0 + s1, k, 64);
        double x  = rowb[t];                           // own element of column k
        double x1 = __shfl(x, k + 1, 64);

        double alpha = 0.0, u = 0.0, w = 0.0, Kh = 1.0;
        bool run = (sigma > 1e-300);                   // uniform branch
        if (run) {
            double sq = sqrt(sigma);
            alpha = (x1 >= 0.0) ? -sq : sq;
            Kh = sigma - x1 * alpha;                   // = u^T u / 2 > 0
            u = (t == k + 1) ? (x - alpha) : ((t > k) ? x : 0.0);
        }
        ubuf[t] = u;
        if (t == 0) { dbuf[k] = rowb[k]; ebuf[k] = alpha; }
        __syncthreads();

        if (run) {
            // p_t = (A u)_t / Kh  — full-width: ubuf[j]=0 for j<=k
            double p0 = 0.0, p1 = 0.0;
            #pragma unroll
            for (int j = 0; j < 32; ++j) {
                double2 uv = *(const double2*)&ubuf[2 * j];
                p0 += A[2 * j]     * uv.x;
                p1 += A[2 * j + 1] * uv.y;
            }
            double p = (t > k) ? (p0 + p1) / Kh : 0.0;
            double cc = wsum(u * p) / (2.0 * Kh);
            w = p - cc * u;
        }
        wbuf[t] = w;
        __syncthreads();

        if (run) {
            // rank-2 update — full-width: ubuf/wbuf zero for j<=k; u=w=0 for t<=k
            #pragma unroll
            for (int j = 0; j < 32; ++j) {
                double2 uv = *(const double2*)&ubuf[2 * j];
                double2 wv = *(const double2*)&wbuf[2 * j];
                A[2 * j]     -= u * wv.x + w * uv.x;
                A[2 * j + 1] -= u * wv.y + w * uv.y;
            }
        }
        // next iteration's rowb dump is ordered by the barrier at loop top
    }

    if (t == 62) dbuf[62] = A[62];
    if (t == 63) { dbuf[63] = A[63]; ebuf[62] = A[62]; }
    if (t == 0)  ebuf[63] = 0.0;
    __syncthreads();

    double* tg = trid + (size_t)g * 128;
    tg[t]      = dbuf[t];
    tg[64 + t] = ebuf[t];
}

// ---------------------------------------------------------------------------
// Kernel 3: bisection (Sturm sign-count) per eigenvalue; descending + log-clip.
// ---------------------------------------------------------------------------
__global__ __launch_bounds__(64) void bisect_kernel(const double* __restrict__ trid,
                                                    float* __restrict__ out)
{
    __shared__ double dd[64];
    __shared__ double e2[64];
    __shared__ double ea[64];

    int g = blockIdx.x;
    int t = threadIdx.x;
    const double* tg = trid + (size_t)g * 128;

    double dv = tg[t];
    double ev = tg[64 + t];
    dd[t] = dv;
    ea[t] = fabs(ev);
    e2[t] = ev * ev;
    __syncthreads();

    double el  = (t > 0) ? ea[t - 1] : 0.0;
    double er  = (t < 63) ? ea[t] : 0.0;
    double rad = el + er;
    double lo = wmin(dv - rad);
    double hi = wmax(dv + rad);
    double mid0 = 0.5 * (lo + hi);
    double half = (0.5 * (hi - lo) + 1e-12) * 1.0000001;
    double a = mid0 - half;
    double b = mid0 + half;

    for (int it = 0; it < 34; ++it) {
        double xm = 0.5 * (a + b);
        double pm = 1.0;
        double p  = dd[0] - xm;
        int cnt = (p < 0.0);
        #pragma unroll
        for (int i = 1; i < 64; ++i) {
            double pi = (dd[i] - xm) * p - e2[i - 1] * pm;
            cnt += ((pi < 0.0) != (p < 0.0));
            double ap = fabs(pi);
            double s = (ap > 1e150) ? 1e-150 : ((ap < 1e-150) ? 1e150 : 1.0);
            pm = p * s;
            p  = pi * s;
        }
        if (cnt > t) b = xm; else a = xm;
    }

    double lam = 0.5 * (a + b);
    double v = fmax(lam, 1e-8);
    out[(size_t)g * 64 + (63 - t)] = (float)log(v);
}

// ---------------------------------------------------------------------------
extern "C" void kernel_launch(void* const* d_in, const int* in_sizes, int n_in,
                              void* d_out, int out_size, void* d_ws, size_t ws_size,
                              hipStream_t stream)
{
    const float* X    = (const float*)d_in[0]; // [2048,2048] fp32
    const float* Wt   = (const float*)d_in[1]; // [4096,2048] fp32
    const float* bias = (const float*)d_in[2]; // [4096] fp32
    const float* regp = (const float*)d_in[3]; // [1] fp32

    char* w = (char*)d_ws;
    float*  M    = (float*)w;                        // 32 MB
    double* trid = (double*)(w + 33554432);          // 2 MB
    float* out = (float*)d_out;                      // [2048,64] fp32

    const size_t NEED_PLANES = 111149056ull;
    if (ws_size >= NEED_PLANES) {
        unsigned short* Xh = (unsigned short*)(w + 35651584);
        unsigned short* Xm = (unsigned short*)(w + 44040192);
        unsigned short* Xl = (unsigned short*)(w + 52428800);
        unsigned short* Wh = (unsigned short*)(w + 60817408);
        unsigned short* Wm = (unsigned short*)(w + 77594624);
        unsigned short* Wl = (unsigned short*)(w + 94371840);
        split_kernel<<<dim3(12288), dim3(256), 0, stream>>>(X, Wt, Xh, Xm, Xl, Wh, Wm, Wl);
        gemm_64<<<dim3(1024), dim3(256), 0, stream>>>(
            Xh, Xm, Xl, Wh, Wm, Wl, bias, M);
    } else {
        gemm_bt<<<dim3(32, 16), dim3(256), 0, stream>>>(X, Wt, bias, M);
    }
    tridiag_kernel<<<dim3(2048), dim3(64), 0, stream>>>(M, regp, trid);
    bisect_kernel<<<dim3(2048), dim3(64), 0, stream>>>(trid, out);
}